// Round 2
// baseline (1366.509 us; speedup 1.0000x reference)
//
#include <hip/hip_runtime.h>

#define TOK   8192
#define DD    1024
#define FF    4096
#define EE    8
#define TWOF  8192
#define NSLOT 16384   // TOK * top_k(2)

typedef unsigned short u16;
typedef float  f32x4  __attribute__((ext_vector_type(4)));
typedef __bf16 bf16x8 __attribute__((ext_vector_type(8)));

__device__ __forceinline__ u16 f2b(float f) {
  unsigned u = __builtin_bit_cast(unsigned, f);
  u += 0x7fffu + ((u >> 16) & 1u);   // RNE; inputs finite
  return (u16)(u >> 16);
}

__device__ __forceinline__ void ldslds16(const void* g, void* l) {
  __builtin_amdgcn_global_load_lds((const __attribute__((address_space(1))) void*)g,
                                   (__attribute__((address_space(3))) void*)l, 16, 0, 0);
}

// ---------------- gate: logits, softmax, top-2, counts ----------------
__global__ void gate_kernel(const float* __restrict__ x, const float* __restrict__ gw,
                            const float* __restrict__ gb, int* __restrict__ counts,
                            int* __restrict__ eidx, int* __restrict__ epos,
                            float* __restrict__ ew) {
  const int wave = threadIdx.x >> 6, lane = threadIdx.x & 63;
  const int t = blockIdx.x * 4 + wave;
  float acc[EE] = {0,0,0,0,0,0,0,0};
  const float* xr = x + (size_t)t * DD;
  for (int d = lane; d < DD; d += 64) {
    float xv = xr[d];
    const float* g = gw + (size_t)d * EE;
#pragma unroll
    for (int e = 0; e < EE; ++e) acc[e] += xv * g[e];
  }
#pragma unroll
  for (int e = 0; e < EE; ++e)
#pragma unroll
    for (int off = 32; off > 0; off >>= 1) acc[e] += __shfl_down(acc[e], off);
  if (lane == 0) {
    float l[EE];
#pragma unroll
    for (int e = 0; e < EE; ++e) l[e] = acc[e] + gb[e];
    int i0 = 0;
    for (int e = 1; e < EE; ++e) if (l[e] > l[i0]) i0 = e;
    int i1 = (i0 == 0) ? 1 : 0;
    for (int e = 0; e < EE; ++e) { if (e == i0) continue; if (l[e] > l[i1]) i1 = e; }
    float m = l[0];
    for (int e = 1; e < EE; ++e) m = fmaxf(m, l[e]);
    float s = 0.f, p[EE];
    for (int e = 0; e < EE; ++e) { p[e] = __expf(l[e] - m); s += p[e]; }
    float w0 = p[i0] / s, w1 = p[i1] / s;
    int p0 = atomicAdd(&counts[i0], 1);
    int p1 = atomicAdd(&counts[i1], 1);
    eidx[2*t] = i0; eidx[2*t+1] = i1;
    epos[2*t] = p0; epos[2*t+1] = p1;
    ew[2*t] = w0;  ew[2*t+1] = w1;
  }
}

__global__ void scan_kernel(const int* __restrict__ counts, int* __restrict__ offs) {
  if (threadIdx.x == 0 && blockIdx.x == 0) {
    int s = 0;
    for (int e = 0; e < EE; ++e) { offs[e] = s; s += counts[e]; }
    offs[EE] = s;
  }
}

__global__ void slot_kernel(const int* __restrict__ eidx, const int* __restrict__ epos,
                            const float* __restrict__ ew, const int* __restrict__ offs,
                            int* __restrict__ s2t, float* __restrict__ swt,
                            int* __restrict__ t2s) {
  int i = blockIdx.x * 256 + threadIdx.x;           // 0..2T-1
  int e = eidx[i];
  int slot = offs[e] + epos[i];
  s2t[slot] = i >> 1;
  swt[slot] = ew[i];
  t2s[i] = slot;
}

// ---------------- conversions ----------------
__global__ void cvtx_kernel(const float* __restrict__ x, u16* __restrict__ xb) {
  int i = blockIdx.x * 256 + threadIdx.x;           // 4 elements each
  float4 v = ((const float4*)x)[i];
  unsigned lo = (unsigned)f2b(v.x) | ((unsigned)f2b(v.y) << 16);
  unsigned hi = (unsigned)f2b(v.z) | ((unsigned)f2b(v.w) << 16);
  ((uint2*)xb)[i] = make_uint2(lo, hi);
}

__global__ void gather_kernel(const u16* __restrict__ xb, const int* __restrict__ s2t,
                              u16* __restrict__ xg) {
  int i = blockIdx.x * 256 + threadIdx.x;           // 16B chunks
  int row = i >> 7, c = i & 127;
  int tok = s2t[row];
  ((int4*)xg)[(size_t)row * 128 + c] = ((const int4*)xb)[(size_t)tok * 128 + c];
}

// transpose-convert weights: dst[seg][n][k] (bf16) = src[seg][k][oc(n)] (f32)
__global__ void wt_kernel(const float* __restrict__ srcS, const float* __restrict__ srcR,
                          u16* __restrict__ dst, int K, int N, int permute) {
  __shared__ float tile[32][33];
  const int seg = blockIdx.z;
  const float* src = (seg == 0) ? srcS : srcR + (size_t)(seg - 1) * K * N;
  const int pc0 = blockIdx.x * 32, k0 = blockIdx.y * 32;
  const int tid = threadIdx.x;
  {
    int kk = tid >> 3, j4 = (tid & 7) << 2;
    const float* srow = src + (size_t)(k0 + kk) * N;
#pragma unroll
    for (int q = 0; q < 4; ++q) {
      int n = pc0 + j4 + q;
      int oc = permute ? (((n >> 5) << 4) + (n & 15) + ((n & 16) ? FF : 0)) : n;
      tile[kk][j4 + q] = srow[oc];
    }
  }
  __syncthreads();
  {
    int pp = tid >> 3, kq = (tid & 7) << 2;
    u16* drow = dst + (size_t)seg * N * K + (size_t)(pc0 + pp) * K + k0 + kq;
#pragma unroll
    for (int q = 0; q < 4; ++q) drow[q] = f2b(tile[kq + q][pp]);
  }
}

// ================= 256x256x64 pipelined GEMM core =================
// 8 waves (2M x 4N), per-wave 128x64 out. A ring-3, B ring-2 (160 KiB LDS).
// T2 swizzle: byte ^= (row&7)<<4 (both sides). Counted vmcnt(4) boundaries.

__device__ __forceinline__ void stage_round(const u16* base, long long ldx, int row0,
                                            int rowmax, int kb0, u16* lbuf, int tid, int r) {
  int rloc = r * 64 + (tid >> 3);
  int rg = row0 + rloc; rg = rg > rowmax ? rowmax : rg;
  int col = ((tid & 7) * 16) ^ ((rloc & 7) << 4);
  ldslds16((const char*)base + (size_t)rg * ldx + kb0 + col,
           (char*)lbuf + r * 8192 + tid * 16);
}

__device__ __forceinline__ bf16x8 lds_frag(const u16* buf, int row, int kb) {
  return *(const bf16x8*)((const char*)buf + row * 128 + (kb ^ ((row & 7) << 4)));
}

#define MFMA16(MH) \
  _Pragma("unroll") for (int mi = 0; mi < 4; ++mi) \
  _Pragma("unroll") for (int ni = 0; ni < 4; ++ni) \
    acc[(MH)*4+mi][ni] = __builtin_amdgcn_mfma_f32_16x16x32_bf16(af[mi], bq[ni], acc[(MH)*4+mi][ni], 0, 0, 0);

#define PHASE_SYNC() \
    __builtin_amdgcn_s_barrier(); \
    asm volatile("s_waitcnt lgkmcnt(0)" ::: "memory"); \
    __builtin_amdgcn_sched_barrier(0); \
    __builtin_amdgcn_s_setprio(1)

#define PHASE_END() \
    __builtin_amdgcn_s_setprio(0); \
    __builtin_amdgcn_s_barrier()

template<int NT>
__device__ __forceinline__ void gemm_loop(const u16* Aseg, long long lda, int arow0, int armax,
                                          const u16* Bseg, int brow0,
                                          u16* As, u16* Bs, int tid, int lane, int wm, int wn,
                                          f32x4 (&acc)[8][4]) {
  const long long ldb = (long long)NT * 128;
  const int fr = lane & 15, g16 = (lane >> 4) * 16;
  // prologue: A(0), B(0), A(1) — 12 rounds; steady-state wait leaves A(1) in flight
#pragma unroll
  for (int r = 0; r < 4; ++r) stage_round(Aseg, lda, arow0, armax, 0, As, tid, r);
#pragma unroll
  for (int r = 0; r < 4; ++r) stage_round(Bseg, ldb, brow0, 0x3FFFFFFF, 0, Bs, tid, r);
#pragma unroll
  for (int r = 0; r < 4; ++r) stage_round(Aseg, lda, arow0, armax, 128, As + 16384, tid, r);
  asm volatile("s_waitcnt vmcnt(4)" ::: "memory");
  __builtin_amdgcn_s_barrier();

  int ia = 0, iaw = 2, ib = 0;
  for (int t = 0; t < NT; ++t) {
    const u16* Ab = As + ia * 16384;
    const u16* Bb = Bs + ib * 16384;
    u16* AbW = As + iaw * 16384;
    u16* BbW = Bs + (ib ^ 1) * 16384;
    const bool sB = (t + 1 < NT), sA = (t + 2 < NT);
    bf16x8 af[4], bq[4];

    // ---- phase 0: ks=0, mh=0 (reads B ks0 + A mh0 ks0; stages B(t+1) r0,r1) ----
#pragma unroll
    for (int ni = 0; ni < 4; ++ni) bq[ni] = lds_frag(Bb, wn*64 + ni*16 + fr, g16);
#pragma unroll
    for (int mi = 0; mi < 4; ++mi) af[mi] = lds_frag(Ab, wm*128 + mi*16 + fr, g16);
    if (sB) { stage_round(Bseg, ldb, brow0, 0x3FFFFFFF, (t+1)*128, BbW, tid, 0);
              stage_round(Bseg, ldb, brow0, 0x3FFFFFFF, (t+1)*128, BbW, tid, 1); }
    PHASE_SYNC();
    MFMA16(0);
    PHASE_END();

    // ---- phase 1: ks=0, mh=1 (stages B(t+1) r2,r3) ----
#pragma unroll
    for (int mi = 0; mi < 4; ++mi) af[mi] = lds_frag(Ab, wm*128 + 64 + mi*16 + fr, g16);
    if (sB) { stage_round(Bseg, ldb, brow0, 0x3FFFFFFF, (t+1)*128, BbW, tid, 2);
              stage_round(Bseg, ldb, brow0, 0x3FFFFFFF, (t+1)*128, BbW, tid, 3); }
    PHASE_SYNC();
    MFMA16(1);
    PHASE_END();

    // ---- phase 2: ks=1, mh=0 (reads B ks1; stages A(t+2) r0,r1) ----
#pragma unroll
    for (int ni = 0; ni < 4; ++ni) bq[ni] = lds_frag(Bb, wn*64 + ni*16 + fr, 64 + g16);
#pragma unroll
    for (int mi = 0; mi < 4; ++mi) af[mi] = lds_frag(Ab, wm*128 + mi*16 + fr, 64 + g16);
    if (sA) { stage_round(Aseg, lda, arow0, armax, (t+2)*128, AbW, tid, 0);
              stage_round(Aseg, lda, arow0, armax, (t+2)*128, AbW, tid, 1); }
    PHASE_SYNC();
    MFMA16(0);
    PHASE_END();

    // ---- phase 3: ks=1, mh=1 (stages A(t+2) r2,r3; tile boundary) ----
#pragma unroll
    for (int mi = 0; mi < 4; ++mi) af[mi] = lds_frag(Ab, wm*128 + 64 + mi*16 + fr, 64 + g16);
    if (sA) { stage_round(Aseg, lda, arow0, armax, (t+2)*128, AbW, tid, 2);
              stage_round(Aseg, lda, arow0, armax, (t+2)*128, AbW, tid, 3); }
    PHASE_SYNC();
    MFMA16(1);
    __builtin_amdgcn_s_setprio(0);
    // boundary: counted wait — 4 newest outstanding are A(t+2); all of tile t+1 landed
    if (sA) { asm volatile("s_waitcnt vmcnt(4)" ::: "memory"); }
    else    { asm volatile("s_waitcnt vmcnt(0)" ::: "memory"); }
    __builtin_amdgcn_s_barrier();

    ia = (ia == 2) ? 0 : ia + 1;
    iaw = (iaw == 2) ? 0 : iaw + 1;
    ib ^= 1;
  }
}

// ---------------- GEMM1: x @ w1t(permuted) -> SwiGLU -> hs bf16 ----------------
__global__ __launch_bounds__(512, 2)
void gemm1_kernel(const u16* __restrict__ xb, const u16* __restrict__ xg,
                  const u16* __restrict__ w1t, const float* __restrict__ sb1,
                  const float* __restrict__ rb1, const int* __restrict__ offs,
                  u16* __restrict__ hs) {
  __shared__ __align__(16) u16 As[3 * 16384];
  __shared__ __align__(16) u16 Bs[2 * 16384];
  const int seg = blockIdx.z;
  int rowstart, rows, hsbase, atot;
  const u16* A;
  if (seg == 0) { A = xb; rowstart = 0; rows = TOK; hsbase = 0; atot = TOK; }
  else {
    int o0 = offs[seg - 1], o1 = offs[seg];
    A = xg; rowstart = o0; rows = o1 - o0; hsbase = TOK + o0; atot = NSLOT;
  }
  const int tm = blockIdx.y;
  if (tm * 256 >= rows) return;
  const int tn = blockIdx.x;
  const int tid = threadIdx.x, lane = tid & 63, wid = tid >> 6;
  const int wm = wid >> 2, wn = wid & 3;

  f32x4 acc[8][4] = {};
  gemm_loop<16>(A, (long long)DD * 2, rowstart + tm * 256, atot - 1,
                w1t + (size_t)seg * TWOF * DD, tn * 256,
                As, Bs, tid, lane, wm, wn, acc);

  const int fr = lane & 15, lq = lane >> 4;
  const int rlim = rows - tm * 256;
  const float* b1 = (seg == 0) ? sb1 : rb1 + (size_t)(seg - 1) * TWOF;
  u16* hbase = hs + (size_t)(hsbase + tm * 256) * FF;
#pragma unroll
  for (int p = 0; p < 2; ++p) {
    const int f = (tn * 8 + wn * 2 + p) * 16 + fr;
    const float ba = b1[f], bb = b1[FF + f];
#pragma unroll
    for (int a = 0; a < 8; ++a)
#pragma unroll
      for (int q = 0; q < 4; ++q) {
        int lr = wm * 128 + (a >> 2) * 64 + (a & 3) * 16 + lq * 4 + q;
        if (lr < rlim) {
          float av = acc[a][2*p][q] + ba;
          float bv = acc[a][2*p+1][q] + bb;
          float sv = av / (1.0f + __expf(-av)) * bv;
          hbase[(size_t)lr * FF + f] = f2b(sv);
        }
      }
  }
}

// ---------------- GEMM2: hs @ w2t -> yo (f32, all segments) ----------------
__global__ __launch_bounds__(512, 2)
void gemm2_kernel(const u16* __restrict__ hs, const u16* __restrict__ w2t,
                  const float* __restrict__ sb2, const float* __restrict__ rb2,
                  const int* __restrict__ offs, float* __restrict__ yo) {
  __shared__ __align__(16) u16 As[3 * 16384];
  __shared__ __align__(16) u16 Bs[2 * 16384];
  const int seg = blockIdx.z;
  int rows, hrow0;
  if (seg == 0) { rows = TOK; hrow0 = 0; }
  else {
    int o0 = offs[seg - 1], o1 = offs[seg];
    rows = o1 - o0; hrow0 = TOK + o0;
  }
  const int tm = blockIdx.y;
  if (tm * 256 >= rows) return;
  const int tn = blockIdx.x;
  const int tid = threadIdx.x, lane = tid & 63, wid = tid >> 6;
  const int wm = wid >> 2, wn = wid & 3;

  f32x4 acc[8][4] = {};
  gemm_loop<64>(hs, (long long)FF * 2, hrow0 + tm * 256, 0x3FFFFFFF,
                w2t + (size_t)seg * DD * FF, tn * 256,
                As, Bs, tid, lane, wm, wn, acc);

  const int fr = lane & 15, lq = lane >> 4;
  const int rlim = rows - tm * 256;
  const float* b2 = (seg == 0) ? sb2 : rb2 + (size_t)(seg - 1) * DD;
  float* ybase = yo + (size_t)(hrow0 + tm * 256) * DD;
#pragma unroll
  for (int ni = 0; ni < 4; ++ni) {
    const int c = tn * 256 + wn * 64 + ni * 16 + fr;
    const float bias = b2[c];
#pragma unroll
    for (int a = 0; a < 8; ++a)
#pragma unroll
      for (int q = 0; q < 4; ++q) {
        int lr = wm * 128 + (a >> 2) * 64 + (a & 3) * 16 + lq * 4 + q;
        if (lr < rlim) ybase[(size_t)lr * DD + c] = acc[a][ni][q] + bias;
      }
  }
}

// ---------------- combine: out[t] = yo[t] + w0*yo[T+s0] + w1*yo[T+s1] ----------------
__global__ void combine_kernel(const float* __restrict__ yo, const int* __restrict__ t2s,
                               const float* __restrict__ ew, float* __restrict__ out) {
  const int t = blockIdx.x, d = threadIdx.x;   // 256 threads x 4 floats
  const float4 a  = ((const float4*)(yo + (size_t)t * DD))[d];
  const int s0 = t2s[2*t], s1 = t2s[2*t+1];
  const float w0 = ew[2*t], w1 = ew[2*t+1];
  const float4 r0 = ((const float4*)(yo + (size_t)(TOK + s0) * DD))[d];
  const float4 r1 = ((const float4*)(yo + (size_t)(TOK + s1) * DD))[d];
  float4 r;
  r.x = a.x + w0 * r0.x + w1 * r1.x;
  r.y = a.y + w0 * r0.y + w1 * r1.y;
  r.z = a.z + w0 * r0.z + w1 * r1.z;
  r.w = a.w + w0 * r0.w + w1 * r1.w;
  ((float4*)(out + (size_t)t * DD))[d] = r;
}

// ---------------- launch ----------------
extern "C" void kernel_launch(void* const* d_in, const int* in_sizes, int n_in,
                              void* d_out, int out_size, void* d_ws, size_t ws_size,
                              hipStream_t stream) {
  const float* x   = (const float*)d_in[0];
  const float* gw  = (const float*)d_in[1];
  const float* gb  = (const float*)d_in[2];
  const float* sw1 = (const float*)d_in[3];
  const float* sb1 = (const float*)d_in[4];
  const float* sw2 = (const float*)d_in[5];
  const float* sb2 = (const float*)d_in[6];
  const float* rw1 = (const float*)d_in[7];
  const float* rb1 = (const float*)d_in[8];
  const float* rw2 = (const float*)d_in[9];
  const float* rb2 = (const float*)d_in[10];
  float* out = (float*)d_out;

  char* p = (char*)d_ws;
  auto alloc = [&](size_t bytes) { char* r = p; p += (bytes + 255) & ~(size_t)255; return r; };
  int*   counts = (int*)alloc(EE * 4);
  int*   offs   = (int*)alloc((EE + 1) * 4);
  int*   eidx   = (int*)alloc((size_t)2 * TOK * 4);
  int*   epos   = (int*)alloc((size_t)2 * TOK * 4);
  float* ew     = (float*)alloc((size_t)2 * TOK * 4);
  int*   s2t    = (int*)alloc((size_t)NSLOT * 4);
  float* swt    = (float*)alloc((size_t)NSLOT * 4);
  int*   t2s    = (int*)alloc((size_t)2 * TOK * 4);
  u16*   xb     = (u16*)alloc((size_t)TOK * DD * 2);
  u16*   xg     = (u16*)alloc((size_t)NSLOT * DD * 2);
  u16*   w1t    = (u16*)alloc((size_t)9 * TWOF * DD * 2);
  u16*   w2t    = (u16*)alloc((size_t)9 * DD * FF * 2);
  u16*   hs     = (u16*)alloc((size_t)(TOK + NSLOT + 256) * FF * 2);
  // yo aliases w1t: gemm2 runs strictly after gemm1 (same stream); 100.7MB <= 151MB
  float* yo     = (float*)w1t;

  hipMemsetAsync(counts, 0, EE * 4, stream);
  gate_kernel<<<TOK / 4, 256, 0, stream>>>(x, gw, gb, counts, eidx, epos, ew);
  scan_kernel<<<1, 64, 0, stream>>>(counts, offs);
  slot_kernel<<<(2 * TOK) / 256, 256, 0, stream>>>(eidx, epos, ew, offs, s2t, swt, t2s);
  cvtx_kernel<<<(TOK * DD / 4) / 256, 256, 0, stream>>>(x, xb);
  gather_kernel<<<(NSLOT * 128) / 256, 256, 0, stream>>>(xb, s2t, xg);
  wt_kernel<<<dim3(TWOF / 32, DD / 32, 9), 256, 0, stream>>>(sw1, rw1, w1t, DD, TWOF, 1);
  wt_kernel<<<dim3(DD / 32, FF / 32, 9), 256, 0, stream>>>(sw2, rw2, w2t, FF, DD, 0);
  gemm1_kernel<<<dim3(TWOF / 256, 64, 9), 512, 0, stream>>>(xb, xg, w1t, sb1, rb1, offs, hs);
  gemm2_kernel<<<dim3(DD / 256, 64, 9), 512, 0, stream>>>(hs, w2t, sb2, rb2, offs, yo);
  combine_kernel<<<TOK, 256, 0, stream>>>(yo, t2s, ew, out);
}